// Round 1
// baseline (24101.259 us; speedup 1.0000x reference)
//
#include <hip/hip_runtime.h>
#include <hip/hip_bf16.h>
#include <hip/hip_cooperative_groups.h>

namespace cg = cooperative_groups;

// Problem dims
#define TT 512
#define BB 128
#define DD 1024
#define HH 1024
#define NG 4096    // 4*HH gate columns
#define KT 2048    // DD+HH

// Scan tiling
#define MROWS 32   // batch rows per block
#define KC 256     // K-chunk staged in LDS
#define NCH (KT/KC)

using bf8   = __attribute__((ext_vector_type(8))) short;  // 8 bf16 bit patterns
using f32x4 = __attribute__((ext_vector_type(4))) float;

__device__ __forceinline__ unsigned short f2bf(float f) {
  unsigned int u = __builtin_bit_cast(unsigned int, f);
  u += 0x7fffu + ((u >> 16) & 1u);   // RNE
  return (unsigned short)(u >> 16);
}
__device__ __forceinline__ float sigm(float x) { return 1.0f / (1.0f + __expf(-x)); }
__device__ __forceinline__ float ftanh(float x) {
  float e = __expf(2.0f * x);
  return 1.0f - 2.0f / (e + 1.0f);
}
// Swizzled byte offset into the A-LDS chunk [MROWS][KC] bf16.
__device__ __forceinline__ int a_off(int row, int kbyte) {
  return row * (KC * 2) + (kbyte ^ ((row & 7) << 4));
}

// ---------------- prep kernels ----------------

// Detect resets storage: 1 if byte-packed (bool), 0 if int32.
__global__ void k_detect(const unsigned int* __restrict__ rw, int* __restrict__ flag) {
  __shared__ int any;
  if (threadIdx.x == 0) any = 0;
  __syncthreads();
  int loc = 0;
  for (int i = threadIdx.x; i < (TT * BB) / 4; i += blockDim.x)
    if (rw[i] > 1u) loc = 1;
  if (loc) atomicOr(&any, 1);
  __syncthreads();
  if (threadIdx.x == 0) *flag = any;
}

// Pack W = [Wx; Wh] (KT x NG, f32 row-major) into Wp[n][k] bf16 (N-major).
__global__ void k_pack(const float* __restrict__ Wx, const float* __restrict__ Wh,
                       unsigned short* __restrict__ Wp) {
  __shared__ unsigned short tile[64][65];
  const int kt = blockIdx.x & 31;   // KT/64 = 32
  const int nt = blockIdx.x >> 5;   // NG/64 = 64
  const int k0 = kt * 64, n0 = nt * 64;
  const int t = threadIdx.x;
  {
    const int kl = t >> 2;            // 0..63
    const int nl = (t & 3) * 16;
    const int kg = k0 + kl;
    const float* src = (kg < DD) ? (Wx + (size_t)kg * NG + n0 + nl)
                                 : (Wh + (size_t)(kg - DD) * NG + n0 + nl);
#pragma unroll
    for (int j = 0; j < 16; ++j) tile[kl][nl + j] = f2bf(src[j]);
  }
  __syncthreads();
  {
    const int nl = t >> 2;
    const int kl = (t & 3) * 16;
    unsigned short* dst = Wp + (size_t)(n0 + nl) * KT + k0 + kl;
#pragma unroll
    for (int j = 0; j < 16; ++j) dst[j] = tile[kl + j][nl];
  }
}

// h_buf[0] = resets[0] ? 0 : bf16(h0)
__global__ void k_init(const float* __restrict__ h0, const unsigned char* __restrict__ rB,
                       const int* __restrict__ rI, const int* __restrict__ flag,
                       unsigned short* __restrict__ hbuf) {
  const int i = blockIdx.x * 256 + threadIdx.x;
  if (i >= BB * HH) return;
  const int row = i >> 10;
  const bool r = (*flag) ? (rB[row] != 0) : (rI[row] != 0);
  hbuf[i] = r ? (unsigned short)0 : f2bf(h0[i]);
}

// ---------------- persistent scan kernel ----------------

__global__ void __launch_bounds__(256)
k_scan(const float* __restrict__ obs, const unsigned char* __restrict__ resetsB,
       const int* __restrict__ resetsI, const float* __restrict__ c0,
       const float* __restrict__ bias, const unsigned short* __restrict__ Wp,
       unsigned short* __restrict__ hbuf, const int* __restrict__ flag,
       float* __restrict__ out) {
  __shared__ char Al[MROWS * KC * 2];     // 16 KiB, swizzled bf16 A chunk
  __shared__ float gl[MROWS][4][17];      // gates exchange, padded

  const int tid = threadIdx.x;
  const int wv  = tid >> 6;       // wave = gate type (i,f,g,o)
  const int ln  = tid & 63;
  const int l15 = ln & 15, lhi = ln >> 4;
  const int mb  = blockIdx.x >> 6;   // 0..3
  const int jb  = blockIdx.x & 63;   // 0..63
  const int row0 = mb * MROWS;
  const int byteMode = *flag;

  cg::grid_group grid = cg::this_grid();

  const float bcol = bias[wv * HH + jb * 16 + l15];

  // c-state: thread (u=tid&15, rr=tid>>4) holds rows rr and rr+16
  const int u  = tid & 15;
  const int rr = tid >> 4;
  float c_a = c0[(size_t)(row0 + rr) * HH + jb * 16 + u];
  float c_b = c0[(size_t)(row0 + rr + 16) * HH + jb * 16 + u];

  // staging mapping: 32 bf16 per thread
  const int sr = tid >> 3;          // row 0..31
  const int sk = (tid & 7) * 32;    // k base within chunk

  const unsigned short* bptrBase = Wp + (size_t)(wv * HH + jb * 16 + l15) * KT + lhi * 8;

#pragma unroll 1
  for (int t = 0; t < TT; ++t) {
    const int p = t & 1;
    f32x4 acc0 = {0.f, 0.f, 0.f, 0.f};
    f32x4 acc1 = {0.f, 0.f, 0.f, 0.f};

#pragma unroll 1
    for (int ch = 0; ch < NCH; ++ch) {
      __syncthreads();
      if (ch < 4) {  // x part: f32 -> bf16
        const float* xs = obs + ((size_t)t * BB + row0 + sr) * DD + ch * KC + sk;
#pragma unroll
        for (int j = 0; j < 4; ++j) {
          f32x4 f0 = *(const f32x4*)(xs + j * 8);
          f32x4 f1 = *(const f32x4*)(xs + j * 8 + 4);
          bf8 v;
          v[0] = (short)f2bf(f0[0]); v[1] = (short)f2bf(f0[1]);
          v[2] = (short)f2bf(f0[2]); v[3] = (short)f2bf(f0[3]);
          v[4] = (short)f2bf(f1[0]); v[5] = (short)f2bf(f1[1]);
          v[6] = (short)f2bf(f1[2]); v[7] = (short)f2bf(f1[3]);
          *(bf8*)(Al + a_off(sr, (sk + j * 8) * 2)) = v;
        }
      } else {       // h part: bf16 copy from ping-pong buffer
        const unsigned short* hs =
            hbuf + ((size_t)p * BB + row0 + sr) * HH + (ch - 4) * KC + sk;
#pragma unroll
        for (int j = 0; j < 4; ++j) {
          bf8 v = *(const bf8*)(hs + j * 8);
          *(bf8*)(Al + a_off(sr, (sk + j * 8) * 2)) = v;
        }
      }
      __syncthreads();
      const unsigned short* bp = bptrBase + ch * KC;
#pragma unroll
      for (int kf = 0; kf < 8; ++kf) {
        bf8 bfrag = *(const bf8*)(bp + kf * 32);
        bf8 a0 = *(const bf8*)(Al + a_off(l15,      (kf * 32 + lhi * 8) * 2));
        bf8 a1 = *(const bf8*)(Al + a_off(16 + l15, (kf * 32 + lhi * 8) * 2));
        acc0 = __builtin_amdgcn_mfma_f32_16x16x32_bf16(a0, bfrag, acc0, 0, 0, 0);
        acc1 = __builtin_amdgcn_mfma_f32_16x16x32_bf16(a1, bfrag, acc1, 0, 0, 0);
      }
    }

    // D layout: col = lane&15, row = (lane>>4)*4 + reg  [m89]
#pragma unroll
    for (int q = 0; q < 4; ++q) {
      gl[lhi * 4 + q][wv][l15]      = acc0[q] + bcol;
      gl[16 + lhi * 4 + q][wv][l15] = acc1[q] + bcol;
    }
    __syncthreads();

    // elementwise LSTM update: 2 rows per thread
#pragma unroll
    for (int s = 0; s < 2; ++s) {
      const int r = rr + s * 16;
      const int grow = row0 + r;
      const int ridx = t * BB + grow;
      const bool rcur = byteMode ? (resetsB[ridx] != 0) : (resetsI[ridx] != 0);
      float cold = (s == 0) ? c_a : c_b;
      if (rcur) cold = 0.f;
      const float ig = gl[r][0][u], fg = gl[r][1][u];
      const float gg = gl[r][2][u], og = gl[r][3][u];
      const float nc = sigm(fg) * cold + sigm(ig) * ftanh(gg);
      const float nh = sigm(og) * ftanh(nc);
      if (s == 0) c_a = nc; else c_b = nc;
      out[(size_t)t * BB * HH + (size_t)grow * HH + jb * 16 + u] = nh;
      if (t + 1 < TT) {
        const int ridx2 = (t + 1) * BB + grow;
        const bool rnxt = byteMode ? (resetsB[ridx2] != 0) : (resetsI[ridx2] != 0);
        hbuf[((size_t)(1 - p) * BB + grow) * HH + jb * 16 + u] =
            rnxt ? (unsigned short)0 : f2bf(nh);
      } else {
        out[(size_t)TT * BB * HH + (size_t)grow * HH + jb * 16 + u] = nh;
        out[(size_t)TT * BB * HH + (size_t)BB * HH + (size_t)grow * HH + jb * 16 + u] = nc;
      }
    }

    if (t + 1 < TT) grid.sync();
  }
}

// ---------------- launch ----------------

extern "C" void kernel_launch(void* const* d_in, const int* in_sizes, int n_in,
                              void* d_out, int out_size, void* d_ws, size_t ws_size,
                              hipStream_t stream) {
  const float* obs  = (const float*)d_in[0];
  const void*  rst  = d_in[1];
  const float* h0   = (const float*)d_in[2];
  const float* c0   = (const float*)d_in[3];
  const float* Wx   = (const float*)d_in[4];
  const float* Wh   = (const float*)d_in[5];
  const float* bias = (const float*)d_in[6];
  float* out = (float*)d_out;

  char* ws = (char*)d_ws;
  unsigned short* Wp   = (unsigned short*)ws;                          // 16 MiB
  unsigned short* hbuf = (unsigned short*)(ws + (size_t)NG * KT * 2);  // 512 KiB
  int* flag = (int*)(ws + (size_t)NG * KT * 2 + (size_t)2 * BB * HH * 2);

  const unsigned char* rB = (const unsigned char*)rst;
  const int* rI = (const int*)rst;

  k_detect<<<1, 256, 0, stream>>>((const unsigned int*)rst, flag);
  k_pack<<<dim3((KT / 64) * (NG / 64)), dim3(256), 0, stream>>>(Wx, Wh, Wp);
  k_init<<<dim3((BB * HH) / 256), dim3(256), 0, stream>>>(h0, rB, rI, flag, hbuf);

  void* args[] = { (void*)&obs, (void*)&rB, (void*)&rI, (void*)&c0, (void*)&bias,
                   (void*)&Wp, (void*)&hbuf, (void*)&flag, (void*)&out };
  hipLaunchCooperativeKernel((const void*)k_scan, dim3(256), dim3(256), args, 0, stream);
}